// Round 13
// baseline (238.177 us; speedup 1.0000x reference)
//
#include <hip/hip_runtime.h>
#include <stdint.h>

typedef __attribute__((ext_vector_type(8))) short bf16x8;   // 8 bf16 = 4 VGPRs
typedef __attribute__((ext_vector_type(4))) short s16x4;    // 4 bf16 = 8 B
typedef __attribute__((ext_vector_type(4))) float f32x4;

#define THREADS 256
constexpr int NWIN = 2304;

// d_ws layout (bf16 element offsets)
constexpr int WCATT_E = 0;        // [1536][64]  : col n of [Wq*0.125|Wkv_k|Wkv_v], 64 k contiguous
constexpr int WOT_E   = 98304;    // [64][512]   : col n of Wo, 512 k contiguous
constexpr int POS_E   = 131072;   // [8][64][64]
constexpr size_t WS_NEED = 327680; // bytes

__device__ __forceinline__ short f2bf(float f) {
  uint32_t u = __builtin_bit_cast(uint32_t, f);
  u += 0x7fffu + ((u >> 16) & 1u);          // RNE (finite values)
  return (short)(u >> 16);
}
__device__ __forceinline__ float bf2f(short s) {
  uint32_t u = ((uint32_t)(uint16_t)s) << 16;
  return __builtin_bit_cast(float, u);
}
// 16B-slot XOR key; same involution on write and read sides.
__device__ __forceinline__ int swz(int row, int h) {
  return ((((row ^ (row >> 2) ^ (row >> 3)) & 7) ^ h) << 4);
}

// ---------------- prep: weights -> bf16 transposed in ws ----------------
__global__ void wmsa_prep(const float* __restrict__ Wq, const float* __restrict__ Wkv,
                          const float* __restrict__ Wo, const float* __restrict__ pos,
                          short* __restrict__ ws) {
  int idx = blockIdx.x * 256 + threadIdx.x;
  if (idx < 32768) {                       // Wq -> WcatT[n][k], pre-scaled by 0.125
    int n = idx & 511, k = idx >> 9;
    ws[WCATT_E + n * 64 + k] = f2bf(Wq[k * 512 + n] * 0.125f);
  } else if (idx < 98304) {                // Wkv -> WcatT[512+nkv][k]
    int j = idx - 32768;
    int nkv = j & 1023, k = j >> 10;
    ws[WCATT_E + (512 + nkv) * 64 + k] = f2bf(Wkv[k * 1024 + nkv]);
  } else if (idx < 131072) {               // Wo -> WoT[n][k]
    int j = idx - 98304;
    int n = j & 63, k = j >> 6;
    ws[WOT_E + n * 512 + k] = f2bf(Wo[k * 64 + n]);
  } else if (idx < 163840) {               // pos -> bf16 (natural [h][i][j])
    int j = idx - 131072;
    ws[POS_E + j] = f2bf(pos[j]);
  }
}

// ======== G=3, 768-thread (12-wave), 2-barrier kernel ========
// Per window 48 KB: QP [0,16K) (Q->P->OH), K [16K,32K), VT [32K,48K) — V^T has
// a DEDICATED region so it is scattered in phase 1 (no LDS deps) and bar2/bar3
// of the old pipeline disappear. 144 KB dynamic LDS, 1 block/CU, 12 waves
// (3/SIMD). Phase roles: P1 wave-sections {Q,K,V}x4; P2 (win,hl,ih)=3x2x2;
// P3 (win,ct)=3x4.
__global__ __launch_bounds__(768, 3)
void wmsa_mfma3(const float* __restrict__ x, const float* __restrict__ bo,
                const short* __restrict__ ws, float* __restrict__ out) {
  extern __shared__ __align__(16) char lds[];
  const int tid = threadIdx.x;
  const int wv = tid >> 6;       // 0..11
  const int l  = tid & 63;
  const int lr = l & 15;
  const int lg = l >> 4;

  const int bid  = blockIdx.x;
  const int trip = bid >> 2;         // window triple 0..767
  const int hp   = bid & 3;          // head-pair

  // ---- X fragments for all 3 windows ----
  bf16x8 xa[3][2];
  #pragma unroll
  for (int win = 0; win < 3; ++win) {
    int w   = 3 * trip + win;
    int bb  = w / 576;
    int rem = (w % 576) * 64;
    int hh  = rem / 192;
    int ww0 = rem % 192;
    int src_h = (hh + 4) % 192;
    const float* xp = x + (size_t)(bb * 192 + src_h) * 12288;
    int tok = 16 * hp + lr;
    int sw = ww0 + tok + 4; if (sw >= 192) sw -= 192;
    const float* xq = xp + sw * 64;
    #pragma unroll
    for (int ks = 0; ks < 2; ++ks) {
      float4 a = *(const float4*)(xq + ks * 32 + lg * 8);
      float4 b = *(const float4*)(xq + ks * 32 + lg * 8 + 4);
      bf16x8 v;
      v[0] = f2bf(a.x); v[1] = f2bf(a.y); v[2] = f2bf(a.z); v[3] = f2bf(a.w);
      v[4] = f2bf(b.x); v[5] = f2bf(b.y); v[6] = f2bf(b.z); v[7] = f2bf(b.w);
      xa[win][ks] = v;
    }
  }

  // ---- Phase 1: QKV-GEMM; wave section sect = {0:Q, 1:K, 2:V}, lane-in-sect sl ----
  const int sect = wv >> 2;
  const int sl   = wv & 3;
  if (sect < 2) {
    // Q or K (swapped operands: A=W, B=X): per t, n-tile ntl = sl + 4t.
    // C: n = tile*16 + lg*4 + r -> j8 = t, d0 = sl*16 + lg*4; i = (lr&7)*8 + t.
    const int base = sect * 16384;
    #pragma unroll
    for (int t = 0; t < 8; ++t) {
      int ntl = sl + 4 * t;
      int nload = (sect * 32 + ntl) * 16 + lr;
      bf16x8 b0 = *(const bf16x8*)(ws + WCATT_E + nload * 64 + lg * 8);
      bf16x8 b1 = *(const bf16x8*)(ws + WCATT_E + nload * 64 + 32 + lg * 8);
      int i  = (lr & 7) * 8 + t;
      int h2 = lr >> 3;
      int d0 = sl * 16 + lg * 4;
      int off = base + h2 * 8192 + i * 128 + ((d0 * 2) ^ swz(i, h2));
      #pragma unroll
      for (int win = 0; win < 3; ++win) {
        f32x4 acc = {0.f, 0.f, 0.f, 0.f};
        acc = __builtin_amdgcn_mfma_f32_16x16x32_bf16(b0, xa[win][0], acc, 0, 0, 0);
        acc = __builtin_amdgcn_mfma_f32_16x16x32_bf16(b1, xa[win][1], acc, 0, 0, 0);
        s16x4 pk;
        #pragma unroll
        for (int r = 0; r < 4; ++r) pk[r] = f2bf(acc[r]);
        *(s16x4*)(lds + win * 49152 + off) = pk;
      }
    }
  } else {
    // V (unswapped: A=X, B=Wv): ntile = t*4 + sl -> d-block sl, j8 = t.
    // lane: V[token tl=lg*4+r][d = sl*16+lr], j = (tl&7)*8 + t; pack j-runs of 4.
    #pragma unroll
    for (int g = 0; g < 2; ++g) {
      f32x4 vg[3][4];
      #pragma unroll
      for (int u = 0; u < 4; ++u) {
        int ntile = (g * 4 + u) * 4 + sl;
        int nload = (64 + ntile) * 16 + lr;
        bf16x8 b0 = *(const bf16x8*)(ws + WCATT_E + nload * 64 + lg * 8);
        bf16x8 b1 = *(const bf16x8*)(ws + WCATT_E + nload * 64 + 32 + lg * 8);
        #pragma unroll
        for (int win = 0; win < 3; ++win) {
          f32x4 acc = {0.f, 0.f, 0.f, 0.f};
          acc = __builtin_amdgcn_mfma_f32_16x16x32_bf16(xa[win][0], b0, acc, 0, 0, 0);
          acc = __builtin_amdgcn_mfma_f32_16x16x32_bf16(xa[win][1], b1, acc, 0, 0, 0);
          vg[win][u] = acc;
        }
      }
      int d = sl * 16 + lr;
      #pragma unroll
      for (int win = 0; win < 3; ++win)
        #pragma unroll
        for (int r = 0; r < 4; ++r) {
          int tl = lg * 4 + r;
          int h2 = tl >> 3;
          int jb = (tl & 7) * 16 + g * 8;
          s16x4 pk;
          #pragma unroll
          for (int u = 0; u < 4; ++u) pk[u] = f2bf(vg[win][u][r]);
          *(s16x4*)(lds + win * 49152 + 32768 + h2 * 8192 + d * 128 + (jb ^ swz(d, h2))) = pk;
        }
    }
  }
  __syncthreads();                      // bar1: Q, K, V^T all complete

  // ---- Phase 2: attention; wave role (awin, hl, ih) ----
  const int awin = wv >> 2;
  const int hl   = (wv >> 1) & 1;
  const int ih   = wv & 1;
  const int hglob = 2 * hp + hl;
  char* ldw = lds + awin * 49152;

  s16x4 posr[2][4];
  #pragma unroll
  for (int it = 0; it < 2; ++it) {
    int i = (ih * 2 + it) * 16 + lr;
    const short* pp = ws + POS_E + hglob * 4096 + i * 64;
    #pragma unroll
    for (int jt = 0; jt < 4; ++jt)
      posr[it][jt] = *(const s16x4*)(pp + jt * 16 + lg * 4);
  }

  f32x4 s[2][4];
  #pragma unroll
  for (int it = 0; it < 2; ++it)
    #pragma unroll
    for (int jt = 0; jt < 4; ++jt) s[it][jt] = (f32x4){0.f, 0.f, 0.f, 0.f};

  #pragma unroll
  for (int ks = 0; ks < 2; ++ks) {
    bf16x8 kb[4], qa[2];
    #pragma unroll
    for (int jt = 0; jt < 4; ++jt) {
      int j = jt * 16 + lr;
      kb[jt] = *(const bf16x8*)(ldw + 16384 + hl * 8192 + j * 128 + ((ks * 64 + lg * 16) ^ swz(j, hl)));
    }
    #pragma unroll
    for (int it = 0; it < 2; ++it) {
      int i = (ih * 2 + it) * 16 + lr;
      qa[it] = *(const bf16x8*)(ldw + hl * 8192 + i * 128 + ((ks * 64 + lg * 16) ^ swz(i, hl)));
    }
    __builtin_amdgcn_s_setprio(1);
    #pragma unroll
    for (int it = 0; it < 2; ++it)
      #pragma unroll
      for (int jt = 0; jt < 4; ++jt)
        s[it][jt] = __builtin_amdgcn_mfma_f32_16x16x32_bf16(kb[jt], qa[it], s[it][jt], 0, 0, 0);
    __builtin_amdgcn_s_setprio(0);
  }

  // softmax (row i lane-fixed; no max-subtraction, |sim|<~9 fp32-safe);
  // P overwrites this wave's own Q rows (value depends on qa via MFMA chain)
  #pragma unroll
  for (int it = 0; it < 2; ++it) {
    int i = (ih * 2 + it) * 16 + lr;
    float sum = 0.f;
    #pragma unroll
    for (int jt = 0; jt < 4; ++jt)
      #pragma unroll
      for (int r = 0; r < 4; ++r) {
        float pv = __expf(s[it][jt][r] + bf2f(posr[it][jt][r]));
        s[it][jt][r] = pv;
        sum += pv;
      }
    sum += __shfl_xor(sum, 16);
    sum += __shfl_xor(sum, 32);
    float rinv = 1.f / sum;
    #pragma unroll
    for (int jt = 0; jt < 4; ++jt) {
      s16x4 pk;
      #pragma unroll
      for (int r = 0; r < 4; ++r) pk[r] = f2bf(s[it][jt][r] * rinv);
      *(s16x4*)(ldw + hl * 8192 + i * 128 + ((jt * 32 + lg * 8) ^ swz(i, hl))) = pk;
    }
  }

  // Wo issue-early (short-lived): in flight under PV + OH + bar2; ct = wv&3
  const int ct = wv & 3;
  bf16x8 wofr[16];
  #pragma unroll
  for (int ks = 0; ks < 16; ++ks)
    wofr[ks] = *(const bf16x8*)(ws + WOT_E + (ct * 16 + lr) * 512 + ks * 32 + lg * 8);

  // PV (V^T ready since bar1; P wave-private)
  f32x4 o[2][4];
  #pragma unroll
  for (int it = 0; it < 2; ++it)
    #pragma unroll
    for (int dt = 0; dt < 4; ++dt) o[it][dt] = (f32x4){0.f, 0.f, 0.f, 0.f};
  #pragma unroll
  for (int ks = 0; ks < 2; ++ks) {
    bf16x8 vb[4], pa[2];
    #pragma unroll
    for (int dt = 0; dt < 4; ++dt) {
      int d = dt * 16 + lr;
      vb[dt] = *(const bf16x8*)(ldw + 32768 + hl * 8192 + d * 128 + ((ks * 64 + lg * 16) ^ swz(d, hl)));
    }
    #pragma unroll
    for (int it = 0; it < 2; ++it) {
      int i = (ih * 2 + it) * 16 + lr;
      pa[it] = *(const bf16x8*)(ldw + hl * 8192 + i * 128 + ((ks * 64 + lg * 16) ^ swz(i, hl)));
    }
    __builtin_amdgcn_s_setprio(1);
    #pragma unroll
    for (int it = 0; it < 2; ++it)
      #pragma unroll
      for (int dt = 0; dt < 4; ++dt)
        o[it][dt] = __builtin_amdgcn_mfma_f32_16x16x32_bf16(vb[dt], pa[it], o[it][dt], 0, 0, 0);
    __builtin_amdgcn_s_setprio(0);
  }

  // OH scatter: wave-private rows (this wave's own P byte-range)
  #pragma unroll
  for (int it = 0; it < 2; ++it) {
    int i  = (ih * 2 + it) * 16 + lr;
    int lm = 8 * hl + (i >> 3);
    int rp = lm * 8 + (i & 7);
    #pragma unroll
    for (int dt = 0; dt < 4; ++dt) {
      s16x4 pk;
      #pragma unroll
      for (int r = 0; r < 4; ++r) pk[r] = f2bf(o[it][dt][r]);
      *(s16x4*)(ldw + rp * 128 + ((dt * 32 + lg * 8) ^ swz(rp, 0))) = pk;
    }
  }
  __syncthreads();                      // bar2: OH complete (all windows)

  // ---- Phase 3: Wo for (awin, ct) ----
  f32x4 oacc = {0.f, 0.f, 0.f, 0.f};
  #pragma unroll
  for (int ks = 0; ks < 16; ++ks) {
    int rp = lr * 8 + (ks >> 1);
    int boff = rp * 128 + (((ks & 1) * 64 + lg * 16) ^ swz(rp, 0));
    bf16x8 bfrOH = *(const bf16x8*)(lds + awin * 49152 + boff);
    oacc = __builtin_amdgcn_mfma_f32_16x16x32_bf16(wofr[ks], bfrOH, oacc, 0, 0, 0);
  }
  {
    int c0 = ct * 16 + lg * 4;
    float4 bo4 = *(const float4*)(bo + c0);
    int w   = 3 * trip + awin;
    int bb  = w / 576;
    int rem = (w % 576) * 64;
    int hh  = rem / 192;
    int ww0 = rem % 192;
    int src_h = (hh + 4) % 192;
    float* orow = out + (size_t)(bb * 192 + src_h) * 12288;
    int tok = 16 * hp + lr;
    int sw = ww0 + tok + 4; if (sw >= 192) sw -= 192;
    float4 ov;
    ov.x = oacc[0] + bo4.x; ov.y = oacc[1] + bo4.y;
    ov.z = oacc[2] + bo4.z; ov.w = oacc[3] + bo4.w;
    *(float4*)(orow + sw * 64 + c0) = ov;
  }
}

// ======== G=4 kernel (round-12 verified, 179.8us) — fallback ========
__global__ __launch_bounds__(512, 2)
void wmsa_mfma4(const float* __restrict__ x, const float* __restrict__ bo,
                const short* __restrict__ ws, float* __restrict__ out) {
  extern __shared__ __align__(16) char lds[];
  const int tid = threadIdx.x;
  const int wv = tid >> 6;
  const int l  = tid & 63;
  const int lr = l & 15;
  const int lg = l >> 4;

  const int bid = blockIdx.x;
  const int q   = bid >> 2;
  const int hp  = bid & 3;

  bf16x8 xa[4][2];
  #pragma unroll
  for (int win = 0; win < 4; ++win) {
    int w   = 4 * q + win;
    int bb  = w / 576;
    int rem = (w * 64) % 36864;
    int hh  = rem / 192;
    int ww0 = rem % 192;
    int src_h = (hh + 4) % 192;
    const float* xp = x + (size_t)(bb * 192 + src_h) * 12288;
    int tok = 16 * hp + lr;
    int sw = ww0 + tok + 4; if (sw >= 192) sw -= 192;
    const float* xq = xp + sw * 64;
    #pragma unroll
    for (int ks = 0; ks < 2; ++ks) {
      float4 a = *(const float4*)(xq + ks * 32 + lg * 8);
      float4 b = *(const float4*)(xq + ks * 32 + lg * 8 + 4);
      bf16x8 v;
      v[0] = f2bf(a.x); v[1] = f2bf(a.y); v[2] = f2bf(a.z); v[3] = f2bf(a.w);
      v[4] = f2bf(b.x); v[5] = f2bf(b.y); v[6] = f2bf(b.z); v[7] = f2bf(b.w);
      xa[win][ks] = v;
    }
  }

  #pragma unroll
  for (int t = 0; t < 8; ++t) {
    int nt = wv + 8 * t;
    int nload = nt * 16 + lr;
    bf16x8 b0 = *(const bf16x8*)(ws + WCATT_E + nload * 64 + lg * 8);
    bf16x8 b1 = *(const bf16x8*)(ws + WCATT_E + nload * 64 + 32 + lg * 8);
    const bool isQ = (t < 4);
    int i  = (lr & 7) * 8 + ((nt >> 2) & 7);
    int h2 = lr >> 3;
    int d0 = (nt & 3) * 16 + lg * 4;
    int off = (isQ ? 0 : 16384) + h2 * 8192 + i * 128 + ((d0 * 2) ^ swz(i, h2));
    #pragma unroll
    for (int win = 0; win < 4; ++win) {
      f32x4 acc = {0.f, 0.f, 0.f, 0.f};
      acc = __builtin_amdgcn_mfma_f32_16x16x32_bf16(b0, xa[win][0], acc, 0, 0, 0);
      acc = __builtin_amdgcn_mfma_f32_16x16x32_bf16(b1, xa[win][1], acc, 0, 0, 0);
      s16x4 pk;
      #pragma unroll
      for (int r = 0; r < 4; ++r) pk[r] = f2bf(acc[r]);
      *(s16x4*)(lds + win * 32768 + off) = pk;
    }
  }

  const int bq = wv & 3, aq = wv >> 2;
  f32x4 vacc[4][4];
  #pragma unroll
  for (int u = 0; u < 4; ++u) {
    int ntile = (aq * 4 + u) * 4 + bq;
    int nload = (64 + ntile) * 16 + lr;
    bf16x8 b0 = *(const bf16x8*)(ws + WCATT_E + nload * 64 + lg * 8);
    bf16x8 b1 = *(const bf16x8*)(ws + WCATT_E + nload * 64 + 32 + lg * 8);
    #pragma unroll
    for (int win = 0; win < 4; ++win) {
      f32x4 acc = {0.f, 0.f, 0.f, 0.f};
      acc = __builtin_amdgcn_mfma_f32_16x16x32_bf16(xa[win][0], b0, acc, 0, 0, 0);
      acc = __builtin_amdgcn_mfma_f32_16x16x32_bf16(xa[win][1], b1, acc, 0, 0, 0);
      vacc[win][u] = acc;
    }
  }
  __syncthreads();

  const int hl = (wv >> 1) & 1;
  const int ih = wv & 1;
  const int hglob = 2 * hp + hl;
  const int wbase = aq;

  s16x4 posr[2][4];
  #pragma unroll
  for (int it = 0; it < 2; ++it) {
    int i = (ih * 2 + it) * 16 + lr;
    const short* pp = ws + POS_E + hglob * 4096 + i * 64;
    #pragma unroll
    for (int jt = 0; jt < 4; ++jt)
      posr[it][jt] = *(const s16x4*)(pp + jt * 16 + lg * 4);
  }

  #pragma unroll
  for (int c = 0; c < 2; ++c) {
    char* ldw = lds + (wbase + 2 * c) * 32768;
    f32x4 s[2][4];
    #pragma unroll
    for (int it = 0; it < 2; ++it)
      #pragma unroll
      for (int jt = 0; jt < 4; ++jt) s[it][jt] = (f32x4){0.f, 0.f, 0.f, 0.f};

    #pragma unroll
    for (int ks = 0; ks < 2; ++ks) {
      bf16x8 kb[4], qa[2];
      #pragma unroll
      for (int jt = 0; jt < 4; ++jt) {
        int j = jt * 16 + lr;
        kb[jt] = *(const bf16x8*)(ldw + 16384 + hl * 8192 + j * 128 + ((ks * 64 + lg * 16) ^ swz(j, hl)));
      }
      #pragma unroll
      for (int it = 0; it < 2; ++it) {
        int i = (ih * 2 + it) * 16 + lr;
        qa[it] = *(const bf16x8*)(ldw + hl * 8192 + i * 128 + ((ks * 64 + lg * 16) ^ swz(i, hl)));
      }
      __builtin_amdgcn_s_setprio(1);
      #pragma unroll
      for (int it = 0; it < 2; ++it)
        #pragma unroll
        for (int jt = 0; jt < 4; ++jt)
          s[it][jt] = __builtin_amdgcn_mfma_f32_16x16x32_bf16(kb[jt], qa[it], s[it][jt], 0, 0, 0);
      __builtin_amdgcn_s_setprio(0);
    }

    #pragma unroll
    for (int it = 0; it < 2; ++it) {
      int i = (ih * 2 + it) * 16 + lr;
      float sum = 0.f;
      #pragma unroll
      for (int jt = 0; jt < 4; ++jt)
        #pragma unroll
        for (int r = 0; r < 4; ++r) {
          float pv = __expf(s[it][jt][r] + bf2f(posr[it][jt][r]));
          s[it][jt][r] = pv;
          sum += pv;
        }
      sum += __shfl_xor(sum, 16);
      sum += __shfl_xor(sum, 32);
      float rinv = 1.f / sum;
      #pragma unroll
      for (int jt = 0; jt < 4; ++jt) {
        s16x4 pk;
        #pragma unroll
        for (int r = 0; r < 4; ++r) pk[r] = f2bf(s[it][jt][r] * rinv);
        *(s16x4*)(ldw + hl * 8192 + i * 128 + ((jt * 32 + lg * 8) ^ swz(i, hl))) = pk;
      }
    }
  }
  __syncthreads();

  {
    int d = bq * 16 + lr;
    #pragma unroll
    for (int win = 0; win < 4; ++win)
      #pragma unroll
      for (int r = 0; r < 4; ++r) {
        int tl = lg * 4 + r;
        int h2 = tl >> 3;
        int jb = (tl & 7) * 16 + aq * 8;
        s16x4 pk;
        #pragma unroll
        for (int u = 0; u < 4; ++u) pk[u] = f2bf(vacc[win][u][r]);
        *(s16x4*)(lds + win * 32768 + 16384 + h2 * 8192 + d * 128 + (jb ^ swz(d, h2))) = pk;
      }
  }
  __syncthreads();

  bf16x8 wofr[16];
  #pragma unroll
  for (int ks = 0; ks < 16; ++ks)
    wofr[ks] = *(const bf16x8*)(ws + WOT_E + (bq * 16 + lr) * 512 + ks * 32 + lg * 8);

  #pragma unroll
  for (int c = 0; c < 2; ++c) {
    char* ldw = lds + (wbase + 2 * c) * 32768;
    f32x4 o[2][4];
    #pragma unroll
    for (int it = 0; it < 2; ++it)
      #pragma unroll
      for (int dt = 0; dt < 4; ++dt) o[it][dt] = (f32x4){0.f, 0.f, 0.f, 0.f};
    #pragma unroll
    for (int ks = 0; ks < 2; ++ks) {
      bf16x8 vb[4], pa[2];
      #pragma unroll
      for (int dt = 0; dt < 4; ++dt) {
        int d = dt * 16 + lr;
        vb[dt] = *(const bf16x8*)(ldw + 16384 + hl * 8192 + d * 128 + ((ks * 64 + lg * 16) ^ swz(d, hl)));
      }
      #pragma unroll
      for (int it = 0; it < 2; ++it) {
        int i = (ih * 2 + it) * 16 + lr;
        pa[it] = *(const bf16x8*)(ldw + hl * 8192 + i * 128 + ((ks * 64 + lg * 16) ^ swz(i, hl)));
      }
      __builtin_amdgcn_s_setprio(1);
      #pragma unroll
      for (int it = 0; it < 2; ++it)
        #pragma unroll
        for (int dt = 0; dt < 4; ++dt)
          o[it][dt] = __builtin_amdgcn_mfma_f32_16x16x32_bf16(vb[dt], pa[it], o[it][dt], 0, 0, 0);
      __builtin_amdgcn_s_setprio(0);
    }
    #pragma unroll
    for (int it = 0; it < 2; ++it) {
      int i  = (ih * 2 + it) * 16 + lr;
      int lm = 8 * hl + (i >> 3);
      int rp = lm * 8 + (i & 7);
      #pragma unroll
      for (int dt = 0; dt < 4; ++dt) {
        s16x4 pk;
        #pragma unroll
        for (int r = 0; r < 4; ++r) pk[r] = f2bf(o[it][dt][r]);
        *(s16x4*)(ldw + rp * 128 + ((dt * 32 + lg * 8) ^ swz(rp, 0))) = pk;
      }
    }
  }
  __syncthreads();

  f32x4 oacc0 = {0.f, 0.f, 0.f, 0.f};
  f32x4 oacc1 = {0.f, 0.f, 0.f, 0.f};
  #pragma unroll
  for (int ks = 0; ks < 16; ++ks) {
    int rp = lr * 8 + (ks >> 1);
    int boff = rp * 128 + (((ks & 1) * 64 + lg * 16) ^ swz(rp, 0));
    bf16x8 bA = *(const bf16x8*)(lds + wbase * 32768 + boff);
    bf16x8 bB = *(const bf16x8*)(lds + (wbase + 2) * 32768 + boff);
    oacc0 = __builtin_amdgcn_mfma_f32_16x16x32_bf16(wofr[ks], bA, oacc0, 0, 0, 0);
    oacc1 = __builtin_amdgcn_mfma_f32_16x16x32_bf16(wofr[ks], bB, oacc1, 0, 0, 0);
  }
  {
    int c0 = bq * 16 + lg * 4;
    float4 bo4 = *(const float4*)(bo + c0);
    int tok = 16 * hp + lr;
    #pragma unroll
    for (int c = 0; c < 2; ++c) {
      int w   = 4 * q + wbase + 2 * c;
      int bb  = w / 576;
      int rem = (w * 64) % 36864;
      int hh  = rem / 192;
      int ww0 = rem % 192;
      int src_h = (hh + 4) % 192;
      float* orow = out + (size_t)(bb * 192 + src_h) * 12288;
      int sw = ww0 + tok + 4; if (sw >= 192) sw -= 192;
      f32x4 oa = c ? oacc1 : oacc0;
      float4 ov;
      ov.x = oa[0] + bo4.x; ov.y = oa[1] + bo4.y;
      ov.z = oa[2] + bo4.z; ov.w = oa[3] + bo4.w;
      *(float4*)(orow + sw * 64 + c0) = ov;
    }
  }
}

extern "C" void kernel_launch(void* const* d_in, const int* in_sizes, int n_in,
                              void* d_out, int out_size, void* d_ws, size_t ws_size,
                              hipStream_t stream) {
  const float* x    = (const float*)d_in[0];
  const float* Wq   = (const float*)d_in[1];
  const float* Wkv  = (const float*)d_in[2];
  const float* Wo   = (const float*)d_in[3];
  const float* bo   = (const float*)d_in[4];
  const float* pos  = (const float*)d_in[5];
  float* o = (float*)d_out;
  wmsa_prep<<<dim3(640), dim3(256), 0, stream>>>(Wq, Wkv, Wo, pos, (short*)d_ws);
  hipError_t e3 = hipFuncSetAttribute((const void*)wmsa_mfma3,
                                      hipFuncAttributeMaxDynamicSharedMemorySize, 147456);
  if (e3 == hipSuccess) {
    wmsa_mfma3<<<dim3(NWIN / 3 * 4), dim3(768), 147456, stream>>>(x, bo, (const short*)d_ws, o);
  } else {
    hipError_t e4 = hipFuncSetAttribute((const void*)wmsa_mfma4,
                                        hipFuncAttributeMaxDynamicSharedMemorySize, 131072);
    (void)e4;
    wmsa_mfma4<<<dim3(NWIN), dim3(512), 131072, stream>>>(x, bo, (const short*)d_ws, o);
  }
}